// Round 7
// baseline (287.192 us; speedup 1.0000x reference)
//
#include <hip/hip_runtime.h>

#define DN 128
#define DE 64
#define DO 128
#define DIN 320       // 2*DN + DE
#define LDX 72        // padded LDS row stride in bf16 elems (144 B)

typedef short bf16x8 __attribute__((ext_vector_type(8)));
typedef float f32x4 __attribute__((ext_vector_type(4)));
typedef unsigned long long u64;

__device__ inline unsigned short f2bf(float f) {
    unsigned u = __builtin_bit_cast(unsigned, f);
    u = (u + 0x7fffu + ((u >> 16) & 1u)) >> 16;   // round-to-nearest-even
    return (unsigned short)u;
}
__device__ inline unsigned pk2(float a, float b) {
    return (unsigned)f2bf(a) | ((unsigned)f2bf(b) << 16);
}
__device__ inline float bf2f(unsigned short h) {
    unsigned u = ((unsigned)h) << 16;
    return __builtin_bit_cast(float, u);
}

// ---------------------------------------------------------------------------
// 0) convert W [128x320] and nf [N x 128] f32 -> bf16 (one pass, 4 f32/thread)
// ---------------------------------------------------------------------------
__global__ __launch_bounds__(256) void convert_kernel(
    const float* __restrict__ W, const float* __restrict__ nf,
    unsigned short* __restrict__ Wbf, unsigned short* __restrict__ nfbf,
    int nW4, int n4tot)
{
    int i = blockIdx.x * 256 + threadIdx.x;
    if (i >= n4tot) return;
    const float* sp;
    unsigned short* dp;
    int j;
    if (i < nW4) { sp = W;  dp = Wbf;  j = i; }
    else         { sp = nf; dp = nfbf; j = i - nW4; }
    const float4 v = *(const float4*)&sp[(size_t)j * 4];
    u64 val = (u64)pk2(v.x, v.y) | ((u64)pk2(v.z, v.w) << 32);
    *(u64*)&dp[(size_t)j * 4] = val;
}

// ---------------------------------------------------------------------------
// 1) count incoming edges per node (4 edges/thread, int4 loads)
// ---------------------------------------------------------------------------
__global__ __launch_bounds__(256) void count_kernel(
    const int* __restrict__ dst, int* __restrict__ counts, int E)
{
    int t = blockIdx.x * 256 + threadIdx.x;
    int e4 = t * 4;
    if (e4 + 3 < E) {
        int4 d4 = *(const int4*)&dst[e4];
        atomicAdd(&counts[d4.x], 1);
        atomicAdd(&counts[d4.y], 1);
        atomicAdd(&counts[d4.z], 1);
        atomicAdd(&counts[d4.w], 1);
    } else {
        for (int e = e4; e < E; ++e) atomicAdd(&counts[dst[e]], 1);
    }
}

// ---------------------------------------------------------------------------
// 2) exclusive scan of counts -> row_ptr AND cursor (single block, 1024 thr)
//    cursor is a working copy so fill needs NO random row_ptr reads.
// ---------------------------------------------------------------------------
__global__ __launch_bounds__(1024) void scan_kernel(
    const int* __restrict__ counts, int* __restrict__ row_ptr,
    int* __restrict__ cursor, int N, int E)
{
    __shared__ int sdata[1024];
    const int tid = threadIdx.x;
    const int chunk = (((N + 1023) / 1024) + 3) & ~3;   // multiple of 4
    const int start = min(tid * chunk, N);
    const int end = min(start + chunk, N);

    int s = 0;
    int i = start;
    for (; i + 3 < end; i += 4) {
        int4 c4 = *(const int4*)&counts[i];
        s += c4.x + c4.y + c4.z + c4.w;
    }
    for (; i < end; ++i) s += counts[i];
    sdata[tid] = s;
    __syncthreads();
    for (int off = 1; off < 1024; off <<= 1) {
        int t = (tid >= off) ? sdata[tid - off] : 0;
        __syncthreads();
        sdata[tid] += t;
        __syncthreads();
    }
    int run = sdata[tid] - s;
    for (i = start; i < end; ++i) {
        row_ptr[i] = run;
        cursor[i] = run;
        run += counts[i];
    }
    if (tid == 0) row_ptr[N] = E;
}

// ---------------------------------------------------------------------------
// 3) fill (e, src[e]) pairs per destination. cursor starts at row_ptr, so
//    atomicAdd gives the ABSOLUTE slot -> no random row_ptr gather here.
//    4 edges/thread, int4 loads. Pair packed as u64 (lo=e, hi=src).
// ---------------------------------------------------------------------------
__global__ __launch_bounds__(256) void fill_kernel(
    const int* __restrict__ dst, const int* __restrict__ src,
    int* __restrict__ cursor, u64* __restrict__ es, int E)
{
    int t = blockIdx.x * 256 + threadIdx.x;
    int e4 = t * 4;
    if (e4 + 3 < E) {
        int4 d4 = *(const int4*)&dst[e4];
        int4 s4 = *(const int4*)&src[e4];
        int p0 = atomicAdd(&cursor[d4.x], 1);
        int p1 = atomicAdd(&cursor[d4.y], 1);
        int p2 = atomicAdd(&cursor[d4.z], 1);
        int p3 = atomicAdd(&cursor[d4.w], 1);
        es[p0] = (u64)(unsigned)(e4    ) | ((u64)(unsigned)s4.x << 32);
        es[p1] = (u64)(unsigned)(e4 + 1) | ((u64)(unsigned)s4.y << 32);
        es[p2] = (u64)(unsigned)(e4 + 2) | ((u64)(unsigned)s4.z << 32);
        es[p3] = (u64)(unsigned)(e4 + 3) | ((u64)(unsigned)s4.w << 32);
    } else {
        for (int e = e4; e < E; ++e) {
            int pos = atomicAdd(&cursor[dst[e]], 1);
            es[pos] = (u64)(unsigned)e | ((u64)(unsigned)src[e] << 32);
        }
    }
}

// ---------------------------------------------------------------------------
// 4) gather: one wave per node, no atomics; writes MEAN (already /deg) as bf16
//    nf pre-converted bf16: one 16B/lane wave-load = 4 nf rows or 4 ef rows.
//    16 edges unrolled -> 8 wave-loads in flight. ef/es one-pass -> nontemporal.
// ---------------------------------------------------------------------------
__global__ __launch_bounds__(256) void gather_kernel(
    const unsigned short* __restrict__ nfbf, const float* __restrict__ ef,
    const u64* __restrict__ es, const int* __restrict__ row_ptr,
    unsigned short* __restrict__ agg_src_bf,
    unsigned short* __restrict__ agg_edge_bf, int N)
{
    const int wave = threadIdx.x >> 6;
    const int lane = threadIdx.x & 63;
    const int v = blockIdx.x * 4 + wave;
    if (v >= N) return;

    const int start = row_ptr[v];
    const int end = row_ptr[v + 1];
    const int deg = end - start;

    const int g = lane >> 4;     // edge subgroup 0..3
    const int q = lane & 15;     // feature segment within row

    float accN[8];
#pragma unroll
    for (int j = 0; j < 8; ++j) accN[j] = 0.f;
    f32x4 accE = {0.f, 0.f, 0.f, 0.f};

    for (int base = start; base < end; base += 64) {
        const int cnt = min(64, end - base);
        int e_l = 0, s_l = 0;
        if (lane < cnt) {
            u64 p = __builtin_nontemporal_load(&es[base + lane]);
            e_l = (int)(unsigned)(p & 0xffffffffu);
            s_l = (int)(unsigned)(p >> 32);
        }
        for (int i = 0; i < cnt; i += 16) {
            const int s0 = __shfl(s_l, i + g, 64);
            const int s1 = __shfl(s_l, i + 4 + g, 64);
            const int s2 = __shfl(s_l, i + 8 + g, 64);
            const int s3 = __shfl(s_l, i + 12 + g, 64);
            const int e0 = __shfl(e_l, i + g, 64);
            const int e1 = __shfl(e_l, i + 4 + g, 64);
            const int e2 = __shfl(e_l, i + 8 + g, 64);
            const int e3 = __shfl(e_l, i + 12 + g, 64);
            // issue all 8 wave-loads (addresses valid even for tail: id=0)
            bf16x8 n0 = *(const bf16x8*)&nfbf[(size_t)s0 * DN + q * 8];
            bf16x8 n1 = *(const bf16x8*)&nfbf[(size_t)s1 * DN + q * 8];
            bf16x8 n2 = *(const bf16x8*)&nfbf[(size_t)s2 * DN + q * 8];
            bf16x8 n3 = *(const bf16x8*)&nfbf[(size_t)s3 * DN + q * 8];
            f32x4 f0 = __builtin_nontemporal_load((const f32x4*)&ef[(size_t)e0 * DE + q * 4]);
            f32x4 f1 = __builtin_nontemporal_load((const f32x4*)&ef[(size_t)e1 * DE + q * 4]);
            f32x4 f2 = __builtin_nontemporal_load((const f32x4*)&ef[(size_t)e2 * DE + q * 4]);
            f32x4 f3 = __builtin_nontemporal_load((const f32x4*)&ef[(size_t)e3 * DE + q * 4]);
            // predicated accumulate (tail edges contribute 0)
            if (i + g < cnt) {
#pragma unroll
                for (int j = 0; j < 8; ++j) accN[j] += bf2f((unsigned short)n0[j]);
                accE += f0;
            }
            if (i + 4 + g < cnt) {
#pragma unroll
                for (int j = 0; j < 8; ++j) accN[j] += bf2f((unsigned short)n1[j]);
                accE += f1;
            }
            if (i + 8 + g < cnt) {
#pragma unroll
                for (int j = 0; j < 8; ++j) accN[j] += bf2f((unsigned short)n2[j]);
                accE += f2;
            }
            if (i + 12 + g < cnt) {
#pragma unroll
                for (int j = 0; j < 8; ++j) accN[j] += bf2f((unsigned short)n3[j]);
                accE += f3;
            }
        }
    }

    // reduce across the 4 edge subgroups (lanes differing in bits 4,5)
#pragma unroll
    for (int j = 0; j < 8; ++j) {
        accN[j] += __shfl_xor(accN[j], 16, 64);
        accN[j] += __shfl_xor(accN[j], 32, 64);
    }
#pragma unroll
    for (int j = 0; j < 4; ++j) {
        accE[j] += __shfl_xor(accE[j], 16, 64);
        accE[j] += __shfl_xor(accE[j], 32, 64);
    }

    const float inv = (deg > 0) ? (1.0f / (float)deg) : 0.0f;
    if (g == 0) {
        uint4 val;
        val.x = pk2(accN[0] * inv, accN[1] * inv);
        val.y = pk2(accN[2] * inv, accN[3] * inv);
        val.z = pk2(accN[4] * inv, accN[5] * inv);
        val.w = pk2(accN[6] * inv, accN[7] * inv);
        *(uint4*)&agg_src_bf[(size_t)v * DN + q * 8] = val;
    } else if (g == 1) {
        u64 val = (u64)pk2(accE[0] * inv, accE[1] * inv) |
                  ((u64)pk2(accE[2] * inv, accE[3] * inv) << 32);
        *(u64*)&agg_edge_bf[(size_t)v * DE + q * 4] = val;
    }
}

// ---------------------------------------------------------------------------
// 5) finalize (MFMA): out[v] = relu( X[v] @ W^T + b ) ; deg==0 -> relu(nf[v])
//    X[v] = [mean_src(bf16), nfbf(bf16), mean_edge(bf16)]  (320)
//    64 nodes x 128 outs per block; 4 waves; 16x16x32 bf16 MFMA.
// ---------------------------------------------------------------------------
__global__ __launch_bounds__(256) void finalize_kernel(
    const float* __restrict__ nf, const unsigned short* __restrict__ nfbf,
    const unsigned short* __restrict__ Wbf, const float* __restrict__ b,
    const unsigned short* __restrict__ agg_src_bf,
    const unsigned short* __restrict__ agg_edge_bf,
    const int* __restrict__ row_ptr, float* __restrict__ out, int N)
{
    __shared__ unsigned short Ws[DO * LDX];   // 18.4 KB
    __shared__ unsigned short Xs[64 * LDX];   //  9.2 KB
    __shared__ float bs[DO];
    __shared__ int degs[64];

    const int tid = threadIdx.x;
    const int lane = tid & 63;
    const int w = tid >> 6;
    const int node0 = blockIdx.x * 64;

    if (tid < DO) bs[tid] = b[tid];
    if (tid < 64) {
        int v = node0 + tid;
        degs[tid] = (v < N) ? (row_ptr[v + 1] - row_ptr[v]) : 0;
    }

    f32x4 acc[8];
#pragma unroll
    for (int r = 0; r < 8; ++r) acc[r] = (f32x4){0.f, 0.f, 0.f, 0.f};

    for (int c = 0; c < 5; ++c) {
        const int k0 = c * 64;
        __syncthreads();
#pragma unroll
        for (int it = 0; it < 8; ++it) {
            int i4 = tid + it * 256;
            int o = i4 >> 4;
            int kk = (i4 & 15) * 4;
            *(u64*)&Ws[o * LDX + kk] = *(const u64*)&Wbf[o * DIN + k0 + kk];
        }
#pragma unroll
        for (int it = 0; it < 4; ++it) {
            int i4 = tid + it * 256;
            int n = i4 >> 4;
            int kk = (i4 & 15) * 4;
            int v = node0 + n;
            u64 val = 0;
            if (v < N) {
                if (c < 2) {
                    val = *(const u64*)&agg_src_bf[(size_t)v * DN + k0 + kk];
                } else if (c < 4) {
                    val = *(const u64*)&nfbf[(size_t)v * DN + (c - 2) * 64 + kk];
                } else {
                    val = *(const u64*)&agg_edge_bf[(size_t)v * DE + kk];
                }
            }
            *(u64*)&Xs[n * LDX + kk] = val;
        }
        __syncthreads();

        const int xrow = 16 * w + (lane & 15);
        const int kgrp = (lane >> 4) * 8;
#pragma unroll
        for (int t = 0; t < 2; ++t) {
            bf16x8 a = *(const bf16x8*)&Xs[xrow * LDX + t * 32 + kgrp];
#pragma unroll
            for (int r = 0; r < 8; ++r) {
                bf16x8 bw = *(const bf16x8*)&Ws[(16 * r + (lane & 15)) * LDX + t * 32 + kgrp];
                acc[r] = __builtin_amdgcn_mfma_f32_16x16x32_bf16(a, bw, acc[r], 0, 0, 0);
            }
        }
    }

    // epilogue: C layout col=lane&15, row=(lane>>4)*4+reg
    // real BRANCH for the deg==0 path so the nf load is exec-masked away
    // (a ?: select would issue the 25.6 MB nf read for every output).
    const int col = lane & 15;
#pragma unroll
    for (int r = 0; r < 8; ++r) {
        const int o = 16 * r + col;
        const float bo = bs[o];
#pragma unroll
        for (int reg = 0; reg < 4; ++reg) {
            const int n = 16 * w + (lane >> 4) * 4 + reg;
            const int v = node0 + n;
            if (v >= N) continue;
            if (__builtin_expect(degs[n] > 0, 1)) {
                out[(size_t)v * DO + o] = fmaxf(acc[r][reg] + bo, 0.0f);
            } else {
                out[(size_t)v * DO + o] = fmaxf(nf[(size_t)v * DN + o], 0.0f);
            }
        }
    }
}

extern "C" void kernel_launch(void* const* d_in, const int* in_sizes, int n_in,
                              void* d_out, int out_size, void* d_ws, size_t ws_size,
                              hipStream_t stream)
{
    const float* nf  = (const float*)d_in[0];
    const float* ef  = (const float*)d_in[1];
    const float* W   = (const float*)d_in[2];
    const float* b   = (const float*)d_in[3];
    const int*   src = (const int*)d_in[4];
    const int*   dst = (const int*)d_in[5];
    float* out = (float*)d_out;

    const int N = in_sizes[0] / DN;
    const int E = in_sizes[4];

    char* p = (char*)d_ws;
    int* counts  = (int*)p;  p += (size_t)N * 4;
    int* cursor  = (int*)p;  p += (size_t)N * 4;
    int* row_ptr = (int*)p;  p += (size_t)(N + 1) * 4;
    p = (char*)(((uintptr_t)p + 15) & ~(uintptr_t)15);
    u64* es      = (u64*)p;  p += (size_t)E * 8;
    unsigned short* agg_src_bf  = (unsigned short*)p;  p += (size_t)N * DN * 2;
    unsigned short* agg_edge_bf = (unsigned short*)p;  p += (size_t)N * DE * 2;
    unsigned short* nfbf        = (unsigned short*)p;  p += (size_t)N * DN * 2;
    unsigned short* Wbf         = (unsigned short*)p;

    (void)hipMemsetAsync(counts, 0, (size_t)N * sizeof(int), stream);

    const int nW4 = DO * DIN / 4;
    const int n4tot = nW4 + N * DN / 4;
    convert_kernel<<<(n4tot + 255) / 256, 256, 0, stream>>>(W, nf, Wbf, nfbf, nW4, n4tot);

    const int e4b = ((E + 3) / 4 + 255) / 256;
    count_kernel<<<e4b, 256, 0, stream>>>(dst, counts, E);
    scan_kernel<<<1, 1024, 0, stream>>>(counts, row_ptr, cursor, N, E);
    fill_kernel<<<e4b, 256, 0, stream>>>(dst, src, cursor, es, E);

    const int gb = (N + 3) / 4;
    gather_kernel<<<gb, 256, 0, stream>>>(nfbf, ef, es, row_ptr,
                                          agg_src_bf, agg_edge_bf, N);

    const int nb = (N + 63) / 64;
    finalize_kernel<<<nb, 256, 0, stream>>>(nf, nfbf, Wbf, b, agg_src_bf,
                                            agg_edge_bf, row_ptr, out, N);
}